// Round 12
// baseline (104.848 us; speedup 1.0000x reference)
//
#include <hip/hip_runtime.h>
#include <cmath>

#define BB 4
#define TT 8192
#define DD 1024
#define CL 64                // timesteps per chunk (= per block)
#define NCH (TT/CL)          // 128 chunks per chain
#define GRID (BB*NCH)        // 512 blocks (2 per CU, all co-resident)

typedef float fvec4 __attribute__((ext_vector_type(4)));
typedef unsigned long long u64;

// y[b,t,d] = Re(h[t]),  h[t] = r*h[t-1] + x[t],  r = exp(-|a_d|) * cis(w_d)
//
// WIDE fused variant. Lesson R1-R11: every narrow-tile (128B/inst) fused
// kernel pins at ~3 TB/s; R1's pass1 (wave = 64 lanes x fvec4 = 1KB
// contiguous per inst) hit 6.4 TB/s. This kernel keeps that access shape
// for ALL x reads and y writes: block (b, chunk) covers full D; thread owns
// 4 d's in registers; no LDS tile at all.
//   scan (regs, from zero) -> publish agg (sc1) + flag -> lane-parallel
//   poll -> deterministic pipelined Horner walk -> seeded rescan of x
//   (L2/L3-hot, re-read gap is microseconds) -> fvec4 nt y stores.
// Fence-free sc1 protocol (R7): RELAXED agent atomics, per-wave
// s_waitcnt vmcnt(0) + barrier before the single flag store.

__global__ __launch_bounds__(256, 2) void fftconv_fused(
    const float* __restrict__ x, const float* __restrict__ decay,
    const float* __restrict__ freq, u64* __restrict__ agg,
    unsigned* __restrict__ flags, float* __restrict__ y)
{
    const int tid = threadIdx.x;
    const int bid = blockIdx.x;
    const int c   = bid & (NCH-1);       // chunk index (low bits: dispatch order)
    const int b   = bid >> 7;            // NCH=128
    const int d0  = tid << 2;

    // per-channel constants
    fvec4 dcv = *reinterpret_cast<const fvec4*>(decay + d0);
    fvec4 fqv = *reinterpret_cast<const fvec4*>(freq  + d0);
    float rr[4], ri[4], Mr[4], Mi[4];
#pragma unroll
    for (int ch = 0; ch < 4; ++ch) {
        float a = fabsf(dcv[ch]), w = fqv[ch], s, co;
        float e = expf(-a); sincosf(w, &s, &co);
        rr[ch] = e*co; ri[ch] = e*s;                 // r
        e = expf(-a*(float)CL); sincosf(w*(float)CL, &s, &co);
        Mr[ch] = e*co; Mi[ch] = e*s;                 // M = r^CL
    }

    const size_t base = ((size_t)(b*TT + c*CL))*DD + d0;
    const float* xp = x + base;

    // ---- scan from zero state (1KB/inst wave reads, fully unrolled) ----
    float hr[4] = {0,0,0,0}, hi[4] = {0,0,0,0};
#pragma unroll
    for (int t = 0; t < CL; ++t) {
        fvec4 xv = *reinterpret_cast<const fvec4*>(xp + (size_t)t*DD);
#pragma unroll
        for (int ch = 0; ch < 4; ++ch) {
            float nr = fmaf(rr[ch], hr[ch], fmaf(-ri[ch], hi[ch], xv[ch]));
            hi[ch] = fmaf(rr[ch], hi[ch], ri[ch]*hr[ch]);
            hr[ch] = nr;
        }
    }

    // ---- publish chunk aggregate (sc1), then flag after block-wide drain ----
    u64* ab = agg + (size_t)bid*DD + d0;
#pragma unroll
    for (int ch = 0; ch < 4; ++ch) {
        float2 A = make_float2(hr[ch], hi[ch]);
        u64 raw; __builtin_memcpy(&raw, &A, 8);
        __hip_atomic_store(ab + ch, raw, __ATOMIC_RELAXED, __HIP_MEMORY_SCOPE_AGENT);
    }
    asm volatile("s_waitcnt vmcnt(0)" ::: "memory");   // this wave's payload at L3
    __syncthreads();                                    // all waves' payloads at L3
    if (tid == 0)
        __hip_atomic_store(&flags[bid], 1u, __ATOMIC_RELAXED,
                           __HIP_MEMORY_SCOPE_AGENT);

    // ---- poll + deterministic Horner walk over predecessors ----
    float Er[4] = {0,0,0,0}, Ei[4] = {0,0,0,0};
    const u64* wb = agg + (size_t)(bid - c)*DD + d0;    // pred j payload at wb + j*DD

    if (c > 0) {
        // wave 0: lane-parallel poll (lane watches j and j+64)
        if (tid < 64) {
            const unsigned* fb = flags + (bid - c);
            unsigned f1 = (tid      < c) ? 0u : 1u;
            unsigned f2 = (tid + 64 < c) ? 0u : 1u;
            for (;;) {
                if (!f1) f1 = __hip_atomic_load(fb + tid,      __ATOMIC_RELAXED,
                                                __HIP_MEMORY_SCOPE_AGENT);
                if (!f2) f2 = __hip_atomic_load(fb + tid + 64, __ATOMIC_RELAXED,
                                                __HIP_MEMORY_SCOPE_AGENT);
                if (__all(f1 && f2)) break;
                __builtin_amdgcn_s_sleep(1);
            }
        }
        __syncthreads();                   // release all waves for the walk
        asm volatile("" ::: "memory");     // keep payload loads below the poll

        auto loadB = [&](u64 (&Q)[4][4], int J0) {
#pragma unroll
            for (int s2 = 0; s2 < 4; ++s2)
#pragma unroll
                for (int ch2 = 0; ch2 < 4; ++ch2)
                    Q[s2][ch2] = __hip_atomic_load(
                        wb + (size_t)(J0 + s2)*DD + ch2,
                        __ATOMIC_RELAXED, __HIP_MEMORY_SCOPE_AGENT);
        };
        auto accB = [&](u64 (&Q)[4][4]) {
#pragma unroll
            for (int s2 = 0; s2 < 4; ++s2)
#pragma unroll
                for (int ch2 = 0; ch2 < 4; ++ch2) {
                    float2 A; __builtin_memcpy(&A, &Q[s2][ch2], 8);
                    float nr = fmaf(Mr[ch2], Er[ch2], fmaf(-Mi[ch2], Ei[ch2], A.x));
                    Ei[ch2] = fmaf(Mr[ch2], Ei[ch2], fmaf(Mi[ch2], Er[ch2], A.y));
                    Er[ch2] = nr;
                }
        };

        u64 QA[4][4], QB[4][4];
        int j = 0;
        if (c >= 4) loadB(QA, 0);
        for (; j + 8 <= c; j += 8) {       // 4-deep double-buffered pipeline
            loadB(QB, j + 4);
            accB(QA);
            if (j + 12 <= c) loadB(QA, j + 8);
            accB(QB);
        }
        if (j + 4 <= c) { accB(QA); j += 4; }
        for (; j < c; ++j) {               // scalar tail (<=3)
#pragma unroll
            for (int ch = 0; ch < 4; ++ch) {
                u64 raw = __hip_atomic_load(wb + (size_t)j*DD + ch,
                                            __ATOMIC_RELAXED, __HIP_MEMORY_SCOPE_AGENT);
                float2 A; __builtin_memcpy(&A, &raw, 8);
                float nr = fmaf(Mr[ch], Er[ch], fmaf(-Mi[ch], Ei[ch], A.x));
                Ei[ch] = fmaf(Mr[ch], Ei[ch], fmaf(Mi[ch], Er[ch], A.y));
                Er[ch] = nr;
            }
        }
    }

    // ---- seeded rescan (x is L2/L3-hot), wide nt y stores ----
    float* yp = y + base;
#pragma unroll
    for (int ch = 0; ch < 4; ++ch) { hr[ch] = Er[ch]; hi[ch] = Ei[ch]; }
#pragma unroll
    for (int t = 0; t < CL; ++t) {
        fvec4 xv = *reinterpret_cast<const fvec4*>(xp + (size_t)t*DD);
        fvec4 yv;
#pragma unroll
        for (int ch = 0; ch < 4; ++ch) {
            float nr = fmaf(rr[ch], hr[ch], fmaf(-ri[ch], hi[ch], xv[ch]));
            hi[ch] = fmaf(rr[ch], hi[ch], ri[ch]*hr[ch]);
            hr[ch] = nr;
            yv[ch] = nr;
        }
        __builtin_nontemporal_store(yv, reinterpret_cast<fvec4*>(yp + (size_t)t*DD));
    }
}

extern "C" void kernel_launch(void* const* d_in, const int* in_sizes, int n_in,
                              void* d_out, int out_size, void* d_ws, size_t ws_size,
                              hipStream_t stream) {
    const float* x     = (const float*)d_in[0];
    const float* decay = (const float*)d_in[1];
    const float* freq  = (const float*)d_in[2];
    float*       y     = (float*)d_out;

    u64*      agg   = (u64*)d_ws;                             // 512*1024*8 = 4 MB
    unsigned* flags = (unsigned*)((char*)d_ws + (size_t)GRID*DD*sizeof(u64));

    // zero the lookback flags each launch (capture-legal async memset)
    (void)hipMemsetAsync(flags, 0, GRID*sizeof(unsigned), stream);
    fftconv_fused<<<GRID, 256, 0, stream>>>(x, decay, freq, agg, flags, y);
}